// Round 10
// baseline (290.614 us; speedup 1.0000x reference)
//
#include <hip/hip_runtime.h>

#define DIM 768
#define HEADS 12
#define TOK 32768

typedef unsigned short ushort_t;
typedef __attribute__((ext_vector_type(8))) short short8v;   // 8 bf16
typedef __attribute__((ext_vector_type(4))) float f32x4;
typedef __attribute__((ext_vector_type(4))) unsigned short us4;

__device__ __forceinline__ ushort_t f2bf(float x) {
  union { float f; unsigned u; } c; c.f = x;
  unsigned r = (c.u + 0x7FFFu + ((c.u >> 16) & 1u)) >> 16;
  return (ushort_t)r;
}

__device__ __forceinline__ void gload_lds16(const void* g, void* l) {
  __builtin_amdgcn_global_load_lds((const __attribute__((address_space(1))) void*)g,
                                   (__attribute__((address_space(3))) void*)l, 16, 0, 0);
}

#define FENCE asm volatile("" ::: "memory")
#define SCHED0 __builtin_amdgcn_sched_barrier(0)
#define BAR do { FENCE; __builtin_amdgcn_s_barrier(); FENCE; } while (0)
#define LGK0 asm volatile("s_waitcnt lgkmcnt(0)" ::: "memory")
#define LGK8 asm volatile("s_waitcnt lgkmcnt(8)" ::: "memory")
#define VM2  asm volatile("s_waitcnt vmcnt(2)" ::: "memory")
#define VM0  asm volatile("s_waitcnt vmcnt(0)" ::: "memory")

// ---------------- LayerNorm -> bf16 (wave-per-row, float4 loads, us4 stores) ----------------
__global__ __launch_bounds__(256) void ln_kernel(const float* __restrict__ x,
                                                 const float* __restrict__ g,
                                                 const float* __restrict__ be,
                                                 ushort_t* __restrict__ xn) {
  int lane = threadIdx.x & 63;
  int row = blockIdx.x * 4 + (threadIdx.x >> 6);
  const float4* rx = (const float4*)(x + (size_t)row * DIM);
  float4 v[3];
  float s = 0.f, sq = 0.f;
  #pragma unroll
  for (int c = 0; c < 3; ++c) {
    v[c] = rx[lane + 64 * c];
    s  += v[c].x + v[c].y + v[c].z + v[c].w;
    sq += v[c].x * v[c].x + v[c].y * v[c].y + v[c].z * v[c].z + v[c].w * v[c].w;
  }
  #pragma unroll
  for (int off = 32; off; off >>= 1) {
    s  += __shfl_xor(s, off);
    sq += __shfl_xor(sq, off);
  }
  float mu  = s * (1.0f / DIM);
  float var = sq * (1.0f / DIM) - mu * mu;
  float rs  = rsqrtf(var + 1e-5f);
  us4* orow = (us4*)(xn + (size_t)row * DIM);
  const float4* gv = (const float4*)g;
  const float4* bv = (const float4*)be;
  #pragma unroll
  for (int c = 0; c < 3; ++c) {
    float4 gg = gv[lane + 64 * c];
    float4 bb = bv[lane + 64 * c];
    us4 pk;
    pk[0] = f2bf((v[c].x - mu) * rs * gg.x + bb.x);
    pk[1] = f2bf((v[c].y - mu) * rs * gg.y + bb.y);
    pk[2] = f2bf((v[c].z - mu) * rs * gg.z + bb.z);
    pk[3] = f2bf((v[c].w - mu) * rs * gg.w + bb.w);
    orow[lane + 64 * c] = pk;
  }
}

// ---------------- merged weight transpose + bf16 ----------------
__global__ __launch_bounds__(256) void convT2(const float* __restrict__ s0,
                                              ushort_t* __restrict__ d0,
                                              const float* __restrict__ s1,
                                              ushort_t* __restrict__ d1) {
  int z = blockIdx.z;
  if (z && blockIdx.x >= DIM / 32) return;
  const float* src = z ? s1 : s0;
  ushort_t* dst = z ? d1 : d0;
  int Ccol = z ? DIM : 3 * DIM;
  const int R = DIM;
  __shared__ float tile[32][33];
  int c0 = blockIdx.x * 32, r0 = blockIdx.y * 32;
  int tx = threadIdx.x & 31, ty = threadIdx.x >> 5;
  #pragma unroll
  for (int i = 0; i < 32; i += 8)
    tile[ty + i][tx] = src[(size_t)(r0 + ty + i) * Ccol + c0 + tx];
  __syncthreads();
  #pragma unroll
  for (int i = 0; i < 32; i += 8)
    dst[(size_t)(c0 + ty + i) * R + r0 + tx] = f2bf(tile[tx][ty + i]);
}

// ---------------- GEMM1: 256x256 m201-template 8-phase, K=768 ----------------
// Phase: [reads | 1 half-tile stage] -> bar -> lgkm0 -> SCHED0 -> 16 MFMA -> bar.
// Stage ledger: P1-P3,P8 -> odd tile -> d1; P4-P7 -> even tile -> d0.
// Gates: vmcnt(2) at end of P4/P8 only (10 outstanding - 8 needed).
__global__ __launch_bounds__(512, 2) void gemm_8ph(const ushort_t* __restrict__ A,
                                                   const ushort_t* __restrict__ Bt,
                                                   ushort_t* __restrict__ qbf,
                                                   ushort_t* __restrict__ kbf,
                                                   ushort_t* __restrict__ vTbf) {
  extern __shared__ __align__(16) char lds[];
  const int Kb = DIM * 2;
  const int N = 3 * DIM;
  const int nbn = N / 256;   // 9
  const size_t GHalf = (size_t)64 * Kb;

  int bid = blockIdx.x;
  int qd = gridDim.x >> 3;
  int wid = (bid & 7) * qd + (bid >> 3);
  int bm = wid / nbn, bn = wid % nbn;
  int row0 = bm * 256, col0 = bn * 256;
  int t = threadIdx.x;
  int lane = t & 63, wave = t >> 6;
  int wr = wave >> 2, wc = wave & 3;

  const char* Ag = (const char*)A + (size_t)row0 * Kb;
  const char* Bg = (const char*)Bt + (size_t)col0 * Kb;

  int o0 = t * 16;
  int sr = o0 >> 7;
  int skb = (o0 & 127) ^ ((sr & 7) << 4);
  size_t goff = (size_t)sr * Kb + skb;

  // one STG = one 16KB half-tile = 2 gloads
  #define STG(Gbase, Lbase, kt)                                               \
    do {                                                                      \
      gload_lds16((Gbase) + goff + (size_t)(kt) * 128, lds + (Lbase) + o0);   \
      gload_lds16((Gbase) + goff + GHalf + (size_t)(kt) * 128,                \
                  lds + (Lbase) + o0 + 8192);                                 \
    } while (0)

  int fr = lane & 15, fkb = (lane >> 4) << 4;
  int swz = (fr & 7) << 4;
  int kb0 = fkb ^ swz;
  int kb1 = (64 + fkb) ^ swz;
  int laA = (wr * 128 + fr) * 128;
  int laB = 32768 + (wc * 64 + fr) * 128;

  #define LOAD_A(dst, dbase, mq)                                              \
    _Pragma("unroll") for (int mi = 0; mi < 4; ++mi) {                        \
      dst[mi][0] = *(const short8v*)(lds + (dbase) + laA + (mq)*8192 + mi*2048 + kb0); \
      dst[mi][1] = *(const short8v*)(lds + (dbase) + laA + (mq)*8192 + mi*2048 + kb1); \
    }
  #define LOAD_B(dst, dbase, nq)                                              \
    _Pragma("unroll") for (int ni = 0; ni < 2; ++ni) {                        \
      dst[ni][0] = *(const short8v*)(lds + (dbase) + laB + (nq)*4096 + ni*2048 + kb0); \
      dst[ni][1] = *(const short8v*)(lds + (dbase) + laB + (nq)*4096 + ni*2048 + kb1); \
    }
  #define MFMA16(av, bv, mq, nq)                                              \
    do {                                                                      \
      __builtin_amdgcn_s_setprio(1);                                          \
      _Pragma("unroll") for (int mi = 0; mi < 4; ++mi)                        \
        _Pragma("unroll") for (int ni = 0; ni < 2; ++ni) {                    \
          acc[(mq)*4+mi][(nq)*2+ni] = __builtin_amdgcn_mfma_f32_16x16x32_bf16(\
              av[mi][0], bv[ni][0], acc[(mq)*4+mi][(nq)*2+ni], 0, 0, 0);      \
          acc[(mq)*4+mi][(nq)*2+ni] = __builtin_amdgcn_mfma_f32_16x16x32_bf16(\
              av[mi][1], bv[ni][1], acc[(mq)*4+mi][(nq)*2+ni], 0, 0, 0);      \
        }                                                                     \
      __builtin_amdgcn_s_setprio(0);                                          \
      SCHED0;                                                                 \
    } while (0)

  // prologue: t0 full (8 ops) + t1.A-lo (2 ops); gate t0 -> vmcnt(2)
  STG(Ag, 0, 0);  STG(Ag + 128 * Kb, 16384, 0);
  STG(Bg, 32768, 0);  STG(Bg + 128 * Kb, 49152, 0);
  STG(Ag, 65536, 1);
  VM2;
  BAR;

  f32x4 acc[8][4] = {};
  short8v A0[4][2], A1[4][2], B0[2][2], B1[2][2];
  for (int it = 0; it < 6; ++it) {
    const int d0 = 0, d1 = 65536;
    int todd = 2 * it + 1, tev = 2 * it + 2, todd3 = 2 * it + 3;
    bool st = (it < 5);
    // P1: reads A0,B0(d0); stage odd.A-hi -> d1
    LOAD_A(A0, d0, 0); LOAD_B(B0, d0, 0);
    STG(Ag + 128 * Kb, d1 + 16384, todd);
    LGK8;
    BAR; LGK0; SCHED0;
    MFMA16(A0, B0, 0, 0);
    BAR;
    // P2: reads A1(d0); stage odd.B-lo -> d1
    LOAD_A(A1, d0, 1);
    STG(Bg, d1 + 32768, todd);
    BAR; LGK0; SCHED0;
    MFMA16(A1, B0, 1, 0);
    BAR;
    // P3: reads B1(d0); stage odd.B-hi -> d1
    LOAD_B(B1, d0, 1);
    STG(Bg + 128 * Kb, d1 + 49152, todd);
    BAR; LGK0; SCHED0;
    MFMA16(A0, B1, 0, 1);
    BAR;
    // P4: stage even.A-lo -> d0; GATE vmcnt(2) (odd tile fully landed)
    if (st) STG(Ag, d0, tev);
    BAR; SCHED0;
    MFMA16(A1, B1, 1, 1);
    if (st) VM2; else VM0;
    BAR;
    // P5: reads A0,B0(d1); stage even.A-hi -> d0
    LOAD_A(A0, d1, 0); LOAD_B(B0, d1, 0);
    if (st) STG(Ag + 128 * Kb, d0 + 16384, tev);
    LGK8;
    BAR; LGK0; SCHED0;
    MFMA16(A0, B0, 0, 0);
    BAR;
    // P6: reads A1(d1); stage even.B-lo -> d0
    LOAD_A(A1, d1, 1);
    if (st) STG(Bg, d0 + 32768, tev);
    BAR; LGK0; SCHED0;
    MFMA16(A1, B0, 1, 0);
    BAR;
    // P7: reads B1(d1); stage even.B-hi -> d0
    LOAD_B(B1, d1, 1);
    if (st) STG(Bg + 128 * Kb, d0 + 49152, tev);
    BAR; LGK0; SCHED0;
    MFMA16(A0, B1, 0, 1);
    BAR;
    // P8: stage odd'.A-lo -> d1; GATE vmcnt(2) (even tile fully landed)
    if (st) STG(Ag, d1, todd3);
    BAR; SCHED0;
    MFMA16(A1, B1, 1, 1);
    if (st) VM2;
    BAR;
  }
  #undef STG
  #undef LOAD_A
  #undef LOAD_B
  #undef MFMA16

  int rbase = row0 + wr * 128 + ((lane >> 4) << 2);
  int cbase = col0 + wc * 64 + fr;
  #pragma unroll
  for (int m = 0; m < 8; ++m) {
    int r0r = rbase + m * 16;
    #pragma unroll
    for (int n = 0; n < 4; ++n) {
      int c = cbase + n * 16;
      if (c < DIM) {
        #pragma unroll
        for (int j = 0; j < 4; ++j)
          qbf[(size_t)(r0r + j) * DIM + c] = f2bf(fmaxf(acc[m][n][j], 0.0f) + 1e-6f);
      } else if (c < 2 * DIM) {
        #pragma unroll
        for (int j = 0; j < 4; ++j)
          kbf[(size_t)(r0r + j) * DIM + (c - DIM)] = f2bf(fmaxf(acc[m][n][j], 0.0f) + 1e-6f);
      } else {
        int ch = c - 2 * DIM;
        int hh = ch >> 6, e = ch & 63;
        int bb = r0r >> 8, rr = r0r & 255;
        us4 pk;
        #pragma unroll
        for (int j = 0; j < 4; ++j) pk[j] = f2bf(acc[m][n][j]);
        *(us4*)&vTbf[((((size_t)bb * HEADS + hh) * 64 + e) << 8) + rr] = pk;
      }
    }
  }
}

// ---------------- GEMM2: 256x128 m201-template 8-phase ----------------
__global__ __launch_bounds__(512, 2) void gemm_out8(const ushort_t* __restrict__ A,
                                                    const ushort_t* __restrict__ Bt,
                                                    const float* __restrict__ bias,
                                                    float* __restrict__ C) {
  extern __shared__ __align__(16) char lds[];
  const int Kb = DIM * 2;
  const int N = DIM;
  const int nbn = N / 128;   // 6
  const size_t GHalf = (size_t)64 * Kb;

  int bid = blockIdx.x;
  int qd = gridDim.x >> 3;   // 96
  int wid = (bid & 7) * qd + (bid >> 3);
  int bm = wid / nbn, bn = wid % nbn;
  int row0 = bm * 256, col0 = bn * 128;
  int t = threadIdx.x;
  int lane = t & 63, wave = t >> 6;
  int wr = wave >> 2, wc = wave & 3;

  const char* Ag = (const char*)A + (size_t)row0 * Kb;
  const char* Bg = (const char*)Bt + (size_t)col0 * Kb;

  int o0 = t * 16;
  int sr = o0 >> 7;
  int skb = (o0 & 127) ^ ((sr & 7) << 4);
  size_t goff = (size_t)sr * Kb + skb;

  #define STGA(Gbase, Lbase, kt)                                              \
    do {                                                                      \
      gload_lds16((Gbase) + goff + (size_t)(kt) * 128, lds + (Lbase) + o0);   \
      gload_lds16((Gbase) + goff + GHalf + (size_t)(kt) * 128,                \
                  lds + (Lbase) + o0 + 8192);                                 \
    } while (0)
  #define STGB(Gbase, Lbase, kt)                                              \
    gload_lds16((Gbase) + goff + (size_t)(kt) * 128, lds + (Lbase) + o0)

  int fr = lane & 15, fkb = (lane >> 4) << 4;
  int swz = (fr & 7) << 4;
  int kb0 = fkb ^ swz;
  int kb1 = (64 + fkb) ^ swz;
  int laA = (wr * 128 + fr) * 128;
  int laB = 32768 + (wc * 32 + fr) * 128;

  #define LOAD_A(dst, dbase, mq)                                              \
    _Pragma("unroll") for (int mi = 0; mi < 4; ++mi) {                        \
      dst[mi][0] = *(const short8v*)(lds + (dbase) + laA + (mq)*8192 + mi*2048 + kb0); \
      dst[mi][1] = *(const short8v*)(lds + (dbase) + laA + (mq)*8192 + mi*2048 + kb1); \
    }
  #define LOAD_B(dst, dbase, nq)                                              \
    do {                                                                      \
      dst[0] = *(const short8v*)(lds + (dbase) + laB + (nq)*2048 + kb0);      \
      dst[1] = *(const short8v*)(lds + (dbase) + laB + (nq)*2048 + kb1);      \
    } while (0)
  #define MFMA8(av, bv, mq, nq)                                               \
    do {                                                                      \
      __builtin_amdgcn_s_setprio(1);                                          \
      _Pragma("unroll") for (int mi = 0; mi < 4; ++mi) {                      \
        acc[(mq)*4+mi][nq] = __builtin_amdgcn_mfma_f32_16x16x32_bf16(         \
            av[mi][0], bv[0], acc[(mq)*4+mi][nq], 0, 0, 0);                   \
        acc[(mq)*4+mi][nq] = __builtin_amdgcn_mfma_f32_16x16x32_bf16(         \
            av[mi][1], bv[1], acc[(mq)*4+mi][nq], 0, 0, 0);                   \
      }                                                                       \
      __builtin_amdgcn_s_setprio(0);                                          \
      SCHED0;                                                                 \
    } while (0)

  // LDS: d0 = {A 32KB @0, B-lo 8KB @32768, B-hi 8KB @40960}; d1 @49152
  STGA(Ag, 0, 0);  STGA(Ag + 128 * Kb, 16384, 0);
  STGB(Bg, 32768, 0);  STGB(Bg + GHalf, 40960, 0);
  STGA(Ag, 49152, 1);
  VM2;
  BAR;

  f32x4 acc[8][2] = {};
  short8v A0[4][2], A1[4][2], B0[2], B1[2];
  for (int it = 0; it < 6; ++it) {
    const int d0 = 0, d1 = 49152;
    int todd = 2 * it + 1, tev = 2 * it + 2, todd3 = 2 * it + 3;
    bool st = (it < 5);
    // P1
    LOAD_A(A0, d0, 0); LOAD_B(B0, d0, 0);
    STGA(Ag + 128 * Kb, d1 + 16384, todd);
    BAR; LGK0; SCHED0;
    MFMA8(A0, B0, 0, 0);
    BAR;
    // P2
    LOAD_A(A1, d0, 1);
    STGB(Bg, d1 + 32768, todd);
    BAR; LGK0; SCHED0;
    MFMA8(A1, B0, 1, 0);
    BAR;
    // P3
    LOAD_B(B1, d0, 1);
    STGB(Bg + GHalf, d1 + 40960, todd);
    BAR; LGK0; SCHED0;
    MFMA8(A0, B1, 0, 1);
    BAR;
    // P4 + gate
    if (st) STGA(Ag, d0, tev);
    BAR; SCHED0;
    MFMA8(A1, B1, 1, 1);
    if (st) VM2; else VM0;
    BAR;
    // P5
    LOAD_A(A0, d1, 0); LOAD_B(B0, d1, 0);
    if (st) STGA(Ag + 128 * Kb, d0 + 16384, tev);
    BAR; LGK0; SCHED0;
    MFMA8(A0, B0, 0, 0);
    BAR;
    // P6
    LOAD_A(A1, d1, 1);
    if (st) STGB(Bg, d0 + 32768, tev);
    BAR; LGK0; SCHED0;
    MFMA8(A1, B0, 1, 0);
    BAR;
    // P7
    LOAD_B(B1, d1, 1);
    if (st) STGB(Bg + GHalf, d0 + 40960, tev);
    BAR; LGK0; SCHED0;
    MFMA8(A0, B1, 0, 1);
    BAR;
    // P8 + gate
    if (st) STGA(Ag, d1, todd3);
    BAR; SCHED0;
    MFMA8(A1, B1, 1, 1);
    if (st) VM2;
    BAR;
  }
  #undef STGA
  #undef STGB
  #undef LOAD_A
  #undef LOAD_B
  #undef MFMA8

  int rbase = row0 + wr * 128 + ((lane >> 4) << 2);
  int cbase = col0 + wc * 32 + fr;
  #pragma unroll
  for (int m = 0; m < 8; ++m) {
    #pragma unroll
    for (int n = 0; n < 2; ++n) {
      int c = cbase + n * 16;
      float bz = bias[c];
      #pragma unroll
      for (int j = 0; j < 4; ++j)
        C[(size_t)(rbase + m * 16 + j) * N + c] = acc[m][n][j] + bz;
    }
  }
}

// ---------------- attention middle: persistent K+VT, staged K->Q->VT with counted gates ----------------
__global__ __launch_bounds__(512) void attn_fused(const ushort_t* __restrict__ qbf,
                                                  const ushort_t* __restrict__ kbf,
                                                  const ushort_t* __restrict__ vTbf,
                                                  const float* __restrict__ wp,
                                                  ushort_t* __restrict__ attnO) {
  extern __shared__ __align__(16) char lds[];
  const int QOFF = 65536, SOFF = 73728;
  int bh = blockIdx.x;
  int b = bh / HEADS, h = bh % HEADS;
  int t = threadIdx.x;
  int lane = t & 63, wave = t >> 6;
  int fr = lane & 15, fkb = (lane >> 4) << 4;
  int lg4 = (lane >> 4) << 2;

  const char* qg = (const char*)(qbf + ((size_t)b * 256) * DIM + h * 64);
  const char* kg = (const char*)(kbf + ((size_t)b * 256) * DIM + h * 64);
  const char* vg = (const char*)(vTbf + ((size_t)bh << 14));

  #pragma unroll
  for (int is = 0; is < 4; ++is) {
    int o = is * 8192 + t * 16;
    int r = o >> 7;
    int byt = (o & 127) ^ ((r & 7) << 4);
    gload_lds16(kg + (size_t)r * (DIM * 2) + byt, lds + o);
  }
  {
    int o = t * 16;
    int r = o >> 7;
    int byt = (o & 127) ^ ((r & 7) << 4);
    gload_lds16(qg + (size_t)r * (DIM * 2) + byt, lds + QOFF + o);
  }
  #pragma unroll
  for (int is = 0; is < 4; ++is) {
    int o = is * 8192 + t * 16;
    int e = o >> 9;
    int byt = (o & 511) ^ ((e & 7) << 4);
    gload_lds16(vg + e * 512 + byt, lds + 32768 + o);
  }
  asm volatile("s_waitcnt vmcnt(4)" ::: "memory");
  __builtin_amdgcn_s_barrier();

  int wrs = wave & 3, wcs = wave >> 2;
  int wrp = wave >> 2, wcp = wave & 3;

  for (int q4 = 0; q4 < 4; ++q4) {
    f32x4 accA[4][2] = {};
    {
      short8v kf[4][2], qf[2][2];
      #pragma unroll
      for (int mi = 0; mi < 4; ++mi)
        #pragma unroll
        for (int ks = 0; ks < 2; ++ks) {
          int r = wrs * 64 + mi * 16 + fr;
          kf[mi][ks] = *(const short8v*)(lds + r * 128 + ((ks * 64 + fkb) ^ ((r & 7) << 4)));
        }
      #pragma unroll
      for (int ni = 0; ni < 2; ++ni)
        #pragma unroll
        for (int ks = 0; ks < 2; ++ks) {
          int r = wcs * 32 + ni * 16 + fr;
          qf[ni][ks] = *(const short8v*)(lds + QOFF + r * 128 + ((ks * 64 + fkb) ^ ((r & 7) << 4)));
        }
      #pragma unroll
      for (int mi = 0; mi < 4; ++mi)
        #pragma unroll
        for (int ni = 0; ni < 2; ++ni)
          #pragma unroll
          for (int ks = 0; ks < 2; ++ks)
            accA[mi][ni] = __builtin_amdgcn_mfma_f32_16x16x32_bf16(kf[mi][ks], qf[ni][ks],
                                                                   accA[mi][ni], 0, 0, 0);
    }
    BAR;
    #pragma unroll
    for (int mi = 0; mi < 4; ++mi)
      #pragma unroll
      for (int ni = 0; ni < 2; ++ni) {
        float wpf = wp[(q4 * 4 + wcs * 2 + ni) * 16 + wrs * 4 + mi];
        us4 pk;
        #pragma unroll
        for (int j = 0; j < 4; ++j) pk[j] = f2bf(accA[mi][ni][j] * wpf);
        int qrow = wcs * 32 + ni * 16 + fr;
        int sbyte = (wrs * 64 + mi * 16 + lg4) * 2;
        *(us4*)(lds + SOFF + qrow * 512 + (sbyte ^ ((qrow & 7) << 4))) = pk;
      }
    if (q4 < 3) {
      int o = t * 16;
      int r = o >> 7;
      int byt = (o & 127) ^ ((r & 7) << 4);
      gload_lds16(qg + (size_t)((q4 + 1) * 64 + r) * (DIM * 2) + byt, lds + QOFF + o);
    }
    LGK0;
    BAR;
    if (q4 == 0) asm volatile("s_waitcnt vmcnt(1)" ::: "memory");
    f32x4 accB[2] = {{0.f,0.f,0.f,0.f},{0.f,0.f,0.f,0.f}};
    #pragma unroll
    for (int ks = 0; ks < 8; ++ks) {
      int kb = ks * 64 + fkb;
      int e = wcp * 16 + fr;
      short8v bv = *(const short8v*)(lds + 32768 + e * 512 + (kb ^ ((e & 7) << 4)));
      #pragma unroll
      for (int mt = 0; mt < 2; ++mt) {
        int r = wrp * 32 + mt * 16 + fr;
        short8v av = *(const short8v*)(lds + SOFF + r * 512 + (kb ^ ((r & 7) << 4)));
        accB[mt] = __builtin_amdgcn_mfma_f32_16x16x32_bf16(av, bv, accB[mt], 0, 0, 0);
      }
    }
    #pragma unroll
    for (int mt = 0; mt < 2; ++mt) {
      int row = b * 256 + q4 * 64 + wrp * 32 + mt * 16 + lg4;
      int col = h * 64 + wcp * 16 + fr;
      #pragma unroll
      for (int j = 0; j < 4; ++j)
        attnO[(size_t)(row + j) * DIM + col] = f2bf(accB[mt][j]);
    }
    if (q4 < 3) asm volatile("s_waitcnt vmcnt(8)" ::: "memory");
    BAR;
  }
}

extern "C" void kernel_launch(void* const* d_in, const int* in_sizes, int n_in,
                              void* d_out, int out_size, void* d_ws, size_t ws_size,
                              hipStream_t stream) {
  const float* x    = (const float*)d_in[0];
  const float* g    = (const float*)d_in[1];
  const float* be   = (const float*)d_in[2];
  const float* wqkv = (const float*)d_in[3];
  const float* wout = (const float*)d_in[4];
  const float* bout = (const float*)d_in[5];
  const float* wp   = (const float*)d_in[6];
  float* out = (float*)d_out;

  char* w = (char*)d_ws;
  const size_t SZ = (size_t)TOK * DIM * 2;
  ushort_t* qbf   = (ushort_t*)(w);
  ushort_t* kbf   = (ushort_t*)(w + SZ);
  ushort_t* vTbf  = (ushort_t*)(w + 2 * SZ);
  ushort_t* xn    = (ushort_t*)(w + 3 * SZ);
  ushort_t* wqkvT = (ushort_t*)(w + 4 * SZ);
  ushort_t* woutT = (ushort_t*)(w + 4 * SZ + 3538944);
  ushort_t* attnO = xn;

  (void)hipFuncSetAttribute(reinterpret_cast<const void*>(&gemm_8ph),
                            hipFuncAttributeMaxDynamicSharedMemorySize, 131072);
  (void)hipFuncSetAttribute(reinterpret_cast<const void*>(&gemm_out8),
                            hipFuncAttributeMaxDynamicSharedMemorySize, 98304);
  (void)hipFuncSetAttribute(reinterpret_cast<const void*>(&attn_fused),
                            hipFuncAttributeMaxDynamicSharedMemorySize, 106496);

  dim3 gct(3 * DIM / 32, DIM / 32, 2);
  convT2<<<gct, 256, 0, stream>>>(wqkv, wqkvT, wout, woutT);

  ln_kernel<<<TOK / 4, 256, 0, stream>>>(x, g, be, xn);

  gemm_8ph<<<(TOK / 256) * (3 * DIM / 256), 512, 131072, stream>>>(
      xn, wqkvT, qbf, kbf, vTbf);

  attn_fused<<<128 * HEADS, 512, 106496, stream>>>(qbf, kbf, vTbf, wp, attnO);

  gemm_out8<<<(TOK / 256) * (DIM / 128), 512, 98304, stream>>>(
      attnO, woutT, bout, out);
}

// Round 11
// 269.071 us; speedup vs baseline: 1.0801x; 1.0801x over previous
//
#include <hip/hip_runtime.h>

#define DIM 768
#define HEADS 12
#define TOK 32768

typedef unsigned short ushort_t;
typedef __attribute__((ext_vector_type(8))) short short8v;   // 8 bf16
typedef __attribute__((ext_vector_type(4))) float f32x4;
typedef __attribute__((ext_vector_type(4))) unsigned short us4;

__device__ __forceinline__ ushort_t f2bf(float x) {
  union { float f; unsigned u; } c; c.f = x;
  unsigned r = (c.u + 0x7FFFu + ((c.u >> 16) & 1u)) >> 16;
  return (ushort_t)r;
}

__device__ __forceinline__ void gload_lds16(const void* g, void* l) {
  __builtin_amdgcn_global_load_lds((const __attribute__((address_space(1))) void*)g,
                                   (__attribute__((address_space(3))) void*)l, 16, 0, 0);
}

#define FENCE asm volatile("" ::: "memory")
#define SCHED0 __builtin_amdgcn_sched_barrier(0)
#define BARRIER do { FENCE; SCHED0; __builtin_amdgcn_s_barrier(); SCHED0; FENCE; } while (0)
#define LGK0 asm volatile("s_waitcnt lgkmcnt(0)" ::: "memory")
#define VM0  asm volatile("s_waitcnt vmcnt(0)" ::: "memory")
#define VM3  asm volatile("s_waitcnt vmcnt(3)" ::: "memory")

// ---------------- LayerNorm -> bf16 (wave-per-row, float4 loads, us4 stores) ----------------
__global__ __launch_bounds__(256) void ln_kernel(const float* __restrict__ x,
                                                 const float* __restrict__ g,
                                                 const float* __restrict__ be,
                                                 ushort_t* __restrict__ xn) {
  int lane = threadIdx.x & 63;
  int row = blockIdx.x * 4 + (threadIdx.x >> 6);
  const float4* rx = (const float4*)(x + (size_t)row * DIM);
  float4 v[3];
  float s = 0.f, sq = 0.f;
  #pragma unroll
  for (int c = 0; c < 3; ++c) {
    v[c] = rx[lane + 64 * c];
    s  += v[c].x + v[c].y + v[c].z + v[c].w;
    sq += v[c].x * v[c].x + v[c].y * v[c].y + v[c].z * v[c].z + v[c].w * v[c].w;
  }
  #pragma unroll
  for (int off = 32; off; off >>= 1) {
    s  += __shfl_xor(s, off);
    sq += __shfl_xor(sq, off);
  }
  float mu  = s * (1.0f / DIM);
  float var = sq * (1.0f / DIM) - mu * mu;
  float rs  = rsqrtf(var + 1e-5f);
  us4* orow = (us4*)(xn + (size_t)row * DIM);
  const float4* gv = (const float4*)g;
  const float4* bv = (const float4*)be;
  #pragma unroll
  for (int c = 0; c < 3; ++c) {
    float4 gg = gv[lane + 64 * c];
    float4 bb = bv[lane + 64 * c];
    us4 pk;
    pk[0] = f2bf((v[c].x - mu) * rs * gg.x + bb.x);
    pk[1] = f2bf((v[c].y - mu) * rs * gg.y + bb.y);
    pk[2] = f2bf((v[c].z - mu) * rs * gg.z + bb.z);
    pk[3] = f2bf((v[c].w - mu) * rs * gg.w + bb.w);
    orow[lane + 64 * c] = pk;
  }
}

// ---------------- merged weight transpose + bf16 ----------------
__global__ __launch_bounds__(256) void convT2(const float* __restrict__ s0,
                                              ushort_t* __restrict__ d0,
                                              const float* __restrict__ s1,
                                              ushort_t* __restrict__ d1) {
  int z = blockIdx.z;
  if (z && blockIdx.x >= DIM / 32) return;
  const float* src = z ? s1 : s0;
  ushort_t* dst = z ? d1 : d0;
  int Ccol = z ? DIM : 3 * DIM;
  const int R = DIM;
  __shared__ float tile[32][33];
  int c0 = blockIdx.x * 32, r0 = blockIdx.y * 32;
  int tx = threadIdx.x & 31, ty = threadIdx.x >> 5;
  #pragma unroll
  for (int i = 0; i < 32; i += 8)
    tile[ty + i][tx] = src[(size_t)(r0 + ty + i) * Ccol + c0 + tx];
  __syncthreads();
  #pragma unroll
  for (int i = 0; i < 32; i += 8)
    dst[(size_t)(c0 + ty + i) * R + r0 + tx] = f2bf(tile[tx][ty + i]);
}

// ---------------- GEMM1: 256x256 8-phase, pre-issued reads (round-9 best) ----------------
__global__ __launch_bounds__(512, 2) void gemm_8ph(const ushort_t* __restrict__ A,
                                                   const ushort_t* __restrict__ Bt,
                                                   ushort_t* __restrict__ qbf,
                                                   ushort_t* __restrict__ kbf,
                                                   ushort_t* __restrict__ vTbf) {
  extern __shared__ __align__(16) char lds[];
  const int Kb = DIM * 2;
  const int N = 3 * DIM;
  const int nbn = N / 256;   // 9
  const size_t GHalf = (size_t)64 * Kb;

  int bid = blockIdx.x;
  int qd = gridDim.x >> 3;
  int wid = (bid & 7) * qd + (bid >> 3);
  int bm = wid / nbn, bn = wid % nbn;
  int row0 = bm * 256, col0 = bn * 256;
  int t = threadIdx.x;
  int lane = t & 63, wave = t >> 6;
  int wr = wave >> 2, wc = wave & 3;

  const char* Ag = (const char*)A + (size_t)row0 * Kb;
  const char* Bg = (const char*)Bt + (size_t)col0 * Kb;

  int o0 = t * 16;
  int sr = o0 >> 7;
  int skb = (o0 & 127) ^ ((sr & 7) << 4);
  size_t goff = (size_t)sr * Kb + skb;

  #define STG(Gbase, Lbase, kt)                                               \
    do {                                                                      \
      gload_lds16((Gbase) + goff + (size_t)(kt) * 128, lds + (Lbase) + o0);   \
      gload_lds16((Gbase) + goff + GHalf + (size_t)(kt) * 128,                \
                  lds + (Lbase) + o0 + 8192);                                 \
    } while (0)

  int fr = lane & 15, fkb = (lane >> 4) << 4;
  int swz = (fr & 7) << 4;
  int kb0 = fkb ^ swz;
  int kb1 = (64 + fkb) ^ swz;
  int laA = (wr * 128 + fr) * 128;
  int laB = 32768 + (wc * 64 + fr) * 128;

  #define LOAD_A(dst, dbase, mq)                                              \
    _Pragma("unroll") for (int mi = 0; mi < 4; ++mi) {                        \
      dst[mi][0] = *(const short8v*)(lds + (dbase) + laA + (mq)*8192 + mi*2048 + kb0); \
      dst[mi][1] = *(const short8v*)(lds + (dbase) + laA + (mq)*8192 + mi*2048 + kb1); \
    }
  #define LOAD_B(dst, dbase, nq)                                              \
    _Pragma("unroll") for (int ni = 0; ni < 2; ++ni) {                        \
      dst[ni][0] = *(const short8v*)(lds + (dbase) + laB + (nq)*4096 + ni*2048 + kb0); \
      dst[ni][1] = *(const short8v*)(lds + (dbase) + laB + (nq)*4096 + ni*2048 + kb1); \
    }
  #define MFMA16(av, bv, mq, nq)                                              \
    do {                                                                      \
      SCHED0;                                                                 \
      __builtin_amdgcn_s_setprio(1);                                          \
      _Pragma("unroll") for (int mi = 0; mi < 4; ++mi)                        \
        _Pragma("unroll") for (int ni = 0; ni < 2; ++ni) {                    \
          acc[(mq)*4+mi][(nq)*2+ni] = __builtin_amdgcn_mfma_f32_16x16x32_bf16(\
              av[mi][0], bv[ni][0], acc[(mq)*4+mi][(nq)*2+ni], 0, 0, 0);      \
          acc[(mq)*4+mi][(nq)*2+ni] = __builtin_amdgcn_mfma_f32_16x16x32_bf16(\
              av[mi][1], bv[ni][1], acc[(mq)*4+mi][(nq)*2+ni], 0, 0, 0);      \
        }                                                                     \
      __builtin_amdgcn_s_setprio(0);                                          \
    } while (0)

  STG(Ag, 0, 0);  STG(Ag + 128 * Kb, 16384, 0);
  STG(Bg, 32768, 0);  STG(Bg + 128 * Kb, 49152, 0);
  STG(Ag, 65536, 1);  STG(Ag + 128 * Kb, 65536 + 16384, 1);
  STG(Bg, 65536 + 32768, 1);
  asm volatile("s_waitcnt vmcnt(6)" ::: "memory");
  BARRIER;

  short8v aR0[4][2], aR1[4][2], bR0[2][2], bR1[2][2];
  LOAD_A(aR0, 0, 0); LOAD_B(bR0, 0, 0);   // pre-issue for it0.P1

  f32x4 acc[8][4] = {};
  for (int it = 0; it < 6; ++it) {
    const int d0 = 0, d1 = 65536;
    int t1k = 2 * it + 1, t2k = 2 * it + 2, t3k = 2 * it + 3;
    bool st = (it < 5);
    // P1
    LOAD_A(aR1, d0, 1);
    STG(Bg + 128 * Kb, d1 + 49152, t1k);
    MFMA16(aR0, bR0, 0, 0);
    BARRIER;
    // P2
    LOAD_B(bR1, d0, 1);
    MFMA16(aR1, bR0, 1, 0);
    BARRIER;
    // P3 + gate
    if (st) { STG(Ag, d0, t2k); STG(Ag + 128 * Kb, d0 + 16384, t2k); }
    MFMA16(aR0, bR1, 0, 1);
    if (st) asm volatile("s_waitcnt vmcnt(4)" ::: "memory");
    else    asm volatile("s_waitcnt vmcnt(0)" ::: "memory");
    BARRIER;
    // P4
    LOAD_A(aR0, d1, 0); LOAD_B(bR0, d1, 0);
    if (st) STG(Bg, d0 + 32768, t2k);
    MFMA16(aR1, bR1, 1, 1);
    BARRIER;
    // P5
    LOAD_A(aR1, d1, 1);
    if (st) STG(Bg + 128 * Kb, d0 + 49152, t2k);
    MFMA16(aR0, bR0, 0, 0);
    BARRIER;
    // P6
    LOAD_B(bR1, d1, 1);
    MFMA16(aR1, bR0, 1, 0);
    BARRIER;
    // P7 + gate
    if (st) { STG(Ag, d1, t3k); STG(Ag + 128 * Kb, d1 + 16384, t3k); }
    MFMA16(aR0, bR1, 0, 1);
    if (st) asm volatile("s_waitcnt vmcnt(4)" ::: "memory");
    BARRIER;
    // P8
    if (st) {
      LOAD_A(aR0, d0, 0); LOAD_B(bR0, d0, 0);
      STG(Bg, d1 + 32768, t3k);
    }
    MFMA16(aR1, bR1, 1, 1);
    BARRIER;
  }
  #undef STG
  #undef LOAD_A
  #undef LOAD_B
  #undef MFMA16

  int rbase = row0 + wr * 128 + ((lane >> 4) << 2);
  int cbase = col0 + wc * 64 + fr;
  #pragma unroll
  for (int m = 0; m < 8; ++m) {
    int r0r = rbase + m * 16;
    #pragma unroll
    for (int n = 0; n < 4; ++n) {
      int c = cbase + n * 16;
      if (c < DIM) {
        #pragma unroll
        for (int j = 0; j < 4; ++j)
          qbf[(size_t)(r0r + j) * DIM + c] = f2bf(fmaxf(acc[m][n][j], 0.0f) + 1e-6f);
      } else if (c < 2 * DIM) {
        #pragma unroll
        for (int j = 0; j < 4; ++j)
          kbf[(size_t)(r0r + j) * DIM + (c - DIM)] = f2bf(fmaxf(acc[m][n][j], 0.0f) + 1e-6f);
      } else {
        int ch = c - 2 * DIM;
        int hh = ch >> 6, e = ch & 63;
        int bb = r0r >> 8, rr = r0r & 255;
        us4 pk;
        #pragma unroll
        for (int j = 0; j < 4; ++j) pk[j] = f2bf(acc[m][n][j]);
        *(us4*)&vTbf[((((size_t)bb * HEADS + hh) * 64 + e) << 8) + rr] = pk;
      }
    }
  }
}

// ---------------- GEMM2: 256x128, BK=32, ring-2 dbuf 48KB, 2 blocks/CU ----------------
// 512 thr = 8 waves (4Mrow x 2Ncol), wave tile 64x64, acc 64 regs. Slot = A16K + B8K.
__global__ __launch_bounds__(512, 4) void gemm_out8(const ushort_t* __restrict__ A,
                                                    const ushort_t* __restrict__ Bt,
                                                    const float* __restrict__ bias,
                                                    float* __restrict__ C) {
  extern __shared__ __align__(16) char lds[];
  const int Kb = DIM * 2;
  const int N = DIM;
  const int nbn = N / 128;   // 6
  const int NT = DIM / 32;   // 24

  int bid = blockIdx.x;
  int qd = gridDim.x >> 3;   // 96
  int wid = (bid & 7) * qd + (bid >> 3);
  int bm = wid / nbn, bn = wid % nbn;
  int row0 = bm * 256, col0 = bn * 128;
  int t = threadIdx.x;
  int lane = t & 63, wave = t >> 6;
  int wr = wave >> 1, wc = wave & 1;

  const char* Ag = (const char*)A + (size_t)row0 * Kb;
  const char* Bg = (const char*)Bt + (size_t)col0 * Kb;

  // staging: rows are 64B; swizzle byte^=((r&3)<<4)
  int oA0 = t * 16, oA1 = 8192 + t * 16;       // A rows 0..127 / 128..255
  int rA0 = oA0 >> 6, rA1 = oA1 >> 6;
  size_t gA0 = (size_t)rA0 * Kb + ((oA0 & 63) ^ ((rA0 & 3) << 4));
  size_t gA1 = (size_t)rA1 * Kb + ((oA1 & 63) ^ ((rA1 & 3) << 4));
  int oB = t * 16;                              // B rows 0..127
  int rB = oB >> 6;
  size_t gB = (size_t)rB * Kb + ((oB & 63) ^ ((rB & 3) << 4));

  #define STG2(tile, slot)                                                    \
    do {                                                                      \
      char* sb = lds + (slot) * 24576;                                        \
      size_t kk = (size_t)(tile) * 64;                                        \
      gload_lds16(Ag + gA0 + kk, sb + oA0);                                   \
      gload_lds16(Ag + gA1 + kk, sb + oA1);                                   \
      gload_lds16(Bg + gB + kk, sb + 16384 + oB);                             \
    } while (0)

  int fr = lane & 15, fkb = (lane >> 4) << 4;
  int kb = fkb ^ ((fr & 3) << 4);
  int aoff = (wr * 64 + fr) * 64 + kb;          // + mi*1024
  int boff = 16384 + (wc * 64 + fr) * 64 + kb;  // + ni*1024

  STG2(0, 0);

  f32x4 acc[4][4] = {};
  for (int kt = 0; kt < NT; ++kt) {
    int cur = kt & 1;
    if (kt + 1 < NT) { STG2(kt + 1, cur ^ 1); VM3; }
    else VM0;
    BARRIER;
    const char* sb = lds + cur * 24576;
    short8v a[4], b[4];
    #pragma unroll
    for (int mi = 0; mi < 4; ++mi) a[mi] = *(const short8v*)(sb + aoff + mi * 1024);
    #pragma unroll
    for (int ni = 0; ni < 4; ++ni) b[ni] = *(const short8v*)(sb + boff + ni * 1024);
    SCHED0;
    __builtin_amdgcn_s_setprio(1);
    #pragma unroll
    for (int mi = 0; mi < 4; ++mi)
      #pragma unroll
      for (int ni = 0; ni < 4; ++ni)
        acc[mi][ni] = __builtin_amdgcn_mfma_f32_16x16x32_bf16(a[mi], b[ni], acc[mi][ni], 0, 0, 0);
    __builtin_amdgcn_s_setprio(0);
    BARRIER;
  }
  #undef STG2

  int rbase = row0 + wr * 64 + ((lane >> 4) << 2);
  int cbase = col0 + wc * 64 + fr;
  #pragma unroll
  for (int m = 0; m < 4; ++m) {
    #pragma unroll
    for (int n = 0; n < 4; ++n) {
      int c = cbase + n * 16;
      float bz = bias[c];
      #pragma unroll
      for (int j = 0; j < 4; ++j)
        C[(size_t)(rbase + m * 16 + j) * N + c] = acc[m][n][j] + bz;
    }
  }
}

// ---------------- attention middle: K persistent in LDS, VT in REGISTERS, 72KB -> 2 blocks/CU ----
// LDS: K [0,32K) | Q [32K,40K) | S'(+VT initial stage) [40K,72K)
__global__ __launch_bounds__(512, 4) void attn_fused(const ushort_t* __restrict__ qbf,
                                                     const ushort_t* __restrict__ kbf,
                                                     const ushort_t* __restrict__ vTbf,
                                                     const float* __restrict__ wp,
                                                     ushort_t* __restrict__ attnO) {
  extern __shared__ __align__(16) char lds[];
  const int QOFF = 32768, SOFF = 40960;
  int bh = blockIdx.x;
  int b = bh / HEADS, h = bh % HEADS;
  int t = threadIdx.x;
  int lane = t & 63, wave = t >> 6;
  int fr = lane & 15, fkb = (lane >> 4) << 4;
  int lg4 = (lane >> 4) << 2;

  const char* qg = (const char*)(qbf + ((size_t)b * 256) * DIM + h * 64);
  const char* kg = (const char*)(kbf + ((size_t)b * 256) * DIM + h * 64);
  const char* vg = (const char*)(vTbf + ((size_t)bh << 14));

  // stage K (4 ops), Q0 (1 op), VT -> S' region (4 ops)
  #pragma unroll
  for (int is = 0; is < 4; ++is) {
    int o = is * 8192 + t * 16;
    int r = o >> 7;
    int byt = (o & 127) ^ ((r & 7) << 4);
    gload_lds16(kg + (size_t)r * (DIM * 2) + byt, lds + o);
  }
  {
    int o = t * 16;
    int r = o >> 7;
    int byt = (o & 127) ^ ((r & 7) << 4);
    gload_lds16(qg + (size_t)r * (DIM * 2) + byt, lds + QOFF + o);
  }
  #pragma unroll
  for (int is = 0; is < 4; ++is) {
    int o = is * 8192 + t * 16;
    int e = o >> 9;
    int byt = (o & 511) ^ ((e & 7) << 4);
    gload_lds16(vg + e * 512 + byt, lds + SOFF + o);
  }
  VM0;
  __builtin_amdgcn_s_barrier();

  int wrs = wave & 3, wcs = wave >> 2;   // S-GEMM: scol quad, qrow half
  int wrp = wave >> 2, wcp = wave & 3;   // PV: qrow half, e quad

  // VT -> registers (this wave's 16 e-rows x full scol)
  short8v vt[8];
  {
    int e = wcp * 16 + fr;
    int es = (e & 7) << 4;
    #pragma unroll
    for (int ks = 0; ks < 8; ++ks)
      vt[ks] = *(const short8v*)(lds + SOFF + e * 512 + ((ks * 64 + fkb) ^ es));
  }
  LGK0;
  BARRIER;   // all VT reads done before S' overwrites

  for (int q4 = 0; q4 < 4; ++q4) {
    // S^T GEMM: D[scol][qrow] = sum_k K[scol][k] Q[qrow][k]
    f32x4 accA[4][2] = {};
    {
      short8v qf[2][2];
      #pragma unroll
      for (int ni = 0; ni < 2; ++ni) {
        int r = wcs * 32 + ni * 16 + fr;
        int rs = (r & 7) << 4;
        qf[ni][0] = *(const short8v*)(lds + QOFF + r * 128 + (fkb ^ rs));
        qf[ni][1] = *(const short8v*)(lds + QOFF + r * 128 + ((64 + fkb) ^ rs));
      }
      #pragma unroll
      for (int mi = 0; mi < 4; ++mi) {
        int r = wrs * 64 + mi * 16 + fr;
        int rs = (r & 7) << 4;
        short8v kf0 = *(const short8v*)(lds + r * 128 + (fkb ^ rs));
        short8v kf1 = *(const short8v*)(lds + r * 128 + ((64 + fkb) ^ rs));
        #pragma unroll
        for (int ni = 0; ni < 2; ++ni) {
          accA[mi][ni] = __builtin_amdgcn_mfma_f32_16x16x32_bf16(kf0, qf[ni][0], accA[mi][ni], 0, 0, 0);
          accA[mi][ni] = __builtin_amdgcn_mfma_f32_16x16x32_bf16(kf1, qf[ni][1], accA[mi][ni], 0, 0, 0);
        }
      }
    }
    BARRIER;   // K/Q reads + prev PV S'-reads done
    // write S' (wp-scaled, b64) + prefetch next Q
    #pragma unroll
    for (int mi = 0; mi < 4; ++mi)
      #pragma unroll
      for (int ni = 0; ni < 2; ++ni) {
        float wpf = wp[(q4 * 4 + wcs * 2 + ni) * 16 + wrs * 4 + mi];
        us4 pk;
        #pragma unroll
        for (int j = 0; j < 4; ++j) pk[j] = f2bf(accA[mi][ni][j] * wpf);
        int qrow = wcs * 32 + ni * 16 + fr;
        int sbyte = (wrs * 64 + mi * 16 + lg4) * 2;
        *(us4*)(lds + SOFF + qrow * 512 + (sbyte ^ ((qrow & 7) << 4))) = pk;
      }
    if (q4 < 3) {
      int o = t * 16;
      int r = o >> 7;
      int byt = (o & 127) ^ ((r & 7) << 4);
      gload_lds16(qg + (size_t)((q4 + 1) * 64 + r) * (DIM * 2) + byt, lds + QOFF + o);
    }
    LGK0;
    BARRIER;
    // PV: out[qrow][e] = sum_scol S'[qrow][scol] * VT(regs)
    f32x4 accB[2] = {{0.f,0.f,0.f,0.f},{0.f,0.f,0.f,0.f}};
    #pragma unroll
    for (int ks = 0; ks < 8; ++ks) {
      int kbq = ks * 64 + fkb;
      #pragma unroll
      for (int mt = 0; mt < 2; ++mt) {
        int r = wrp * 32 + mt * 16 + fr;
        short8v av = *(const short8v*)(lds + SOFF + r * 512 + (kbq ^ ((r & 7) << 4)));
        accB[mt] = __builtin_amdgcn_mfma_f32_16x16x32_bf16(av, vt[ks], accB[mt], 0, 0, 0);
      }
    }
    #pragma unroll
    for (int mt = 0; mt < 2; ++mt) {
      int row = b * 256 + q4 * 64 + wrp * 32 + mt * 16 + lg4;
      int col = h * 64 + wcp * 16 + fr;
      #pragma unroll
      for (int j = 0; j < 4; ++j)
        attnO[(size_t)(row + j) * DIM + col] = f2bf(accB[mt][j]);
    }
    if (q4 < 3) asm volatile("s_waitcnt vmcnt(8)" ::: "memory");  // next-Q landed; 8 stores younger
    BARRIER;
  }
}

extern "C" void kernel_launch(void* const* d_in, const int* in_sizes, int n_in,
                              void* d_out, int out_size, void* d_ws, size_t ws_size,
                              hipStream_t stream) {
  const float* x    = (const float*)d_in[0];
  const float* g    = (const float*)d_in[1];
  const float* be   = (const float*)d_in[2];
  const float* wqkv = (const float*)d_in[3];
  const float* wout = (const float*)d_in[4];
  const float* bout = (const float*)d_in[5];
  const float* wp   = (const float*)d_in[6];
  float* out = (float*)d_out;

  char* w = (char*)d_ws;
  const size_t SZ = (size_t)TOK * DIM * 2;
  ushort_t* qbf   = (ushort_t*)(w);
  ushort_t* kbf   = (ushort_t*)(w + SZ);
  ushort_t* vTbf  = (ushort_t*)(w + 2 * SZ);
  ushort_t* xn    = (ushort_t*)(w + 3 * SZ);
  ushort_t* wqkvT = (ushort_t*)(w + 4 * SZ);
  ushort_t* woutT = (ushort_t*)(w + 4 * SZ + 3538944);
  ushort_t* attnO = xn;

  (void)hipFuncSetAttribute(reinterpret_cast<const void*>(&gemm_8ph),
                            hipFuncAttributeMaxDynamicSharedMemorySize, 131072);
  (void)hipFuncSetAttribute(reinterpret_cast<const void*>(&gemm_out8),
                            hipFuncAttributeMaxDynamicSharedMemorySize, 49152);
  (void)hipFuncSetAttribute(reinterpret_cast<const void*>(&attn_fused),
                            hipFuncAttributeMaxDynamicSharedMemorySize, 73728);

  dim3 gct(3 * DIM / 32, DIM / 32, 2);
  convT2<<<gct, 256, 0, stream>>>(wqkv, wqkvT, wout, woutT);

  ln_kernel<<<TOK / 4, 256, 0, stream>>>(x, g, be, xn);

  gemm_8ph<<<(TOK / 256) * (3 * DIM / 256), 512, 131072, stream>>>(
      xn, wqkvT, qbf, kbf, vTbf);

  attn_fused<<<128 * HEADS, 512, 73728, stream>>>(qbf, kbf, vTbf, wp, attnO);

  gemm_out8<<<(TOK / 256) * (DIM / 128), 512, 49152, stream>>>(
      attnO, woutT, bout, out);
}